// Round 4
// baseline (72256.451 us; speedup 1.0000x reference)
//
#include <hip/hip_runtime.h>
#include <math.h>

#define TID ((int)threadIdx.x)
#define BID ((int)blockIdx.x)

typedef float4 f4;

// ---- dims ----
constexpr int NB   = 16;
constexpr int TENC = 384;
constexpr int TDEC = 200;
constexpr int HD   = 256;
constexpr int MELD = 400;
constexpr int P2   = 128;
constexpr int G3   = 768;
constexpr int NBLK = 72;    // persistent grid (<=256 CUs -> all co-resident)

// ---- ws layout (float offsets) ----
constexpr int OFF_PM     = 0;                          // [16][384][256]
constexpr int OFF_GIPN   = OFF_PM     + NB*TENC*HD;    // [200][768][16]
constexpr int OFF_PN1    = OFF_GIPN   + TDEC*G3*NB;    // [200][256][16]
constexpr int OFF_PN2    = OFF_PN1    + TDEC*HD*NB;    // [200][128][16]
constexpr int OFF_D2O    = OFF_PN2    + TDEC*P2*NB;    // [200][256][16]
// zeroed region (8*4096 + 256 floats, contiguous):
constexpr int OFF_ATTNH  = OFF_D2O    + TDEC*HD*NB;    // [2][256][16]
constexpr int OFF_CTX    = OFF_ATTNH  + 2*4096;        // [3][256][16]
constexpr int OFF_D1     = OFF_CTX    + 3*4096;        // [2][256][16]
constexpr int OFF_D2     = OFF_D1     + 2*4096;        // [256][16]
constexpr int OFF_BAR    = OFF_D2     + 4096;          // [256] barrier counter (u32 at [0])
// unzeroed state:
constexpr int OFF_DECIN  = OFF_BAR    + 256;           // [2][256][16]
constexpr int OFF_DECIN1 = OFF_DECIN  + 2*4096;        // [2][256][16]
constexpr int OFF_GI     = OFF_DECIN1 + 2*4096;        // [768][16]
constexpr int OFF_GH     = OFF_GI     + 12288;
constexpr int OFF_GI1    = OFF_GH     + 12288;
constexpr int OFF_GH1    = OFF_GI1    + 12288;
constexpr int OFF_GI2    = OFF_GH1    + 12288;
constexpr int OFF_GH2    = OFF_GI2    + 12288;
constexpr int OFF_E      = OFF_GH2    + 12288;         // [16][384]
// transposed weights:
constexpr int OFF_W1T    = OFF_E      + NB*TENC;       // [400][256]
constexpr int OFF_W2T    = OFF_W1T    + 102400;        // [256][128]
constexpr int OFF_WMEMT  = OFF_W2T    + 32768;         // [256][256]
constexpr int OFF_WPNT   = OFF_WMEMT  + 65536;         // [128][768]
constexpr int OFF_WATTT  = OFF_WPNT   + 98304;         // [256][768]
constexpr int OFF_WHHT   = OFF_WATTT  + 196608;        // [256][768]
constexpr int OFF_WQT    = OFF_WHHT   + 196608;        // [256][256]
constexpr int OFF_WPROJT = OFF_WQT    + 65536;         // [512][256]
constexpr int OFF_WIH1T  = OFF_WPROJT + 131072;        // [256][768]
constexpr int OFF_WHH1T  = OFF_WIH1T  + 196608;
constexpr int OFF_WIH2T  = OFF_WHH1T  + 196608;
constexpr int OFF_WHH2T  = OFF_WIH2T  + 196608;
constexpr int OFF_WMELT  = OFF_WHH2T  + 196608;        // [256][400]

__device__ __forceinline__ float fexp2(float x){ return __builtin_amdgcn_exp2f(x); }
__device__ __forceinline__ float frcp(float x){ return __builtin_amdgcn_rcpf(x); }
__device__ __forceinline__ float sigf(float x){ return frcp(1.f + fexp2(-1.44269504f*x)); }
__device__ __forceinline__ float tanhf_(float x){ return 1.f - 2.f*frcp(1.f + fexp2(2.88539008f*x)); }

// ---- monotonic device-scope grid barrier (XCD-safe: agent-scope atomics + fences) ----
__device__ __forceinline__ void gridbar(float* ws, unsigned target_iters){
  unsigned* cnt = (unsigned*)(ws + OFF_BAR);
  __syncthreads();
  if (TID == 0){
    __threadfence();   // release all prior global writes device-wide
    __hip_atomic_fetch_add(cnt, 1u, __ATOMIC_RELEASE, __HIP_MEMORY_SCOPE_AGENT);
    unsigned target = target_iters * NBLK;
    while (__hip_atomic_load(cnt, __ATOMIC_ACQUIRE, __HIP_MEMORY_SCOPE_AGENT) < target){
      __builtin_amdgcn_s_sleep(1);
    }
    __threadfence();   // acquire side
  }
  __syncthreads();
}

// ---------- init: zero recurrent state + barrier (33024 floats) ----------
__global__ void k_init(float* ws){
  int g = BID*256 + TID;
  for (int idx = g; idx < 33024; idx += 32*256) ws[OFF_ATTNH + idx] = 0.f;
}

// ---------- transpose all weight matrices to k-major ----------
__global__ void k_tr(const float* pw1, const float* pw2, const float* wmem,
                     const float* gwih, const float* gwhh, const float* qw,
                     const float* pjw, const float* dwih, const float* dwhh,
                     const float* mw, float* ws){
  int g = BID*256 + TID;
  if (g < 102400){ int j=g%256,k=g/256; ws[OFF_W1T+g]=pw1[j*400+k]; return;} g-=102400;
  if (g < 32768){ int j=g%128,k=g/128; ws[OFF_W2T+g]=pw2[j*256+k]; return;} g-=32768;
  if (g < 65536){ int j=g%256,k=g/256; ws[OFF_WMEMT+g]=wmem[j*256+k]; return;} g-=65536;
  if (g < 98304){ int j=g%768,k=g/768; ws[OFF_WPNT+g]=gwih[j*384+k]; return;} g-=98304;
  if (g < 196608){ int j=g%768,k=g/768; ws[OFF_WATTT+g]=gwih[j*384+128+k]; return;} g-=196608;
  if (g < 196608){ int j=g%768,k=g/768; ws[OFF_WHHT+g]=gwhh[j*256+k]; return;} g-=196608;
  if (g < 65536){ int j=g%256,k=g/256; ws[OFF_WQT+g]=qw[j*256+k]; return;} g-=65536;
  if (g < 131072){ int j=g%256,k=g/256; ws[OFF_WPROJT+g]=pjw[j*512+k]; return;} g-=131072;
  if (g < 196608){ int j=g%768,k=g/768; ws[OFF_WIH1T+g]=dwih[j*256+k]; return;} g-=196608;
  if (g < 196608){ int j=g%768,k=g/768; ws[OFF_WHH1T+g]=dwhh[j*256+k]; return;} g-=196608;
  if (g < 196608){ int j=g%768,k=g/768; ws[OFF_WIH2T+g]=dwih[196608+j*256+k]; return;} g-=196608;
  if (g < 196608){ int j=g%768,k=g/768; ws[OFF_WHH2T+g]=dwhh[196608+j*256+k]; return;} g-=196608;
  if (g < 102400){ int j=g%400,k=g/400; ws[OFF_WMELT+g]=mw[j*256+k]; return;}
}

// ---------- processed_memory = enc @ mem_w^T ----------
__global__ void k_pm(const float* __restrict__ enc, float* __restrict__ ws){
  int b = BID / 24, t0 = (BID % 24) * 16;
  int d = TID;
  const float* W = ws + OFF_WMEMT + d;
  const float* A = enc + (size_t)(b*TENC + t0)*HD;
  float acc[16];
  #pragma unroll
  for (int tt=0; tt<16; ++tt) acc[tt]=0.f;
  for (int k=0; k<HD; k+=4){
    float w0=W[(k+0)*256], w1=W[(k+1)*256], w2=W[(k+2)*256], w3=W[(k+3)*256];
    #pragma unroll
    for (int tt=0; tt<16; ++tt){
      f4 a = *(const f4*)(A + tt*HD + k);
      acc[tt] += w0*a.x + w1*a.y + w2*a.z + w3*a.w;
    }
  }
  float* P = ws + OFF_PM + (size_t)(b*TENC + t0)*HD + d;
  #pragma unroll
  for (int tt=0; tt<16; ++tt) P[tt*HD] = acc[tt];
}

// ---------- prenet layer1 (all steps) ----------
__global__ void k_pre1(const float* __restrict__ inp, const float* __restrict__ pb1, float* __restrict__ ws){
  int t = BID >> 2;
  int j = ((BID & 3) * 64) + (TID & 63);
  int bq = TID >> 6;
  float b = pb1[j];
  float a0=b,a1=b,a2=b,a3=b;
  if (t > 0){
    const float* W = ws + OFF_W1T + j;
    const float* x0 = inp + (size_t)((bq*4+0)*TDEC + (t-1))*MELD;
    const float* x1 = inp + (size_t)((bq*4+1)*TDEC + (t-1))*MELD;
    const float* x2 = inp + (size_t)((bq*4+2)*TDEC + (t-1))*MELD;
    const float* x3 = inp + (size_t)((bq*4+3)*TDEC + (t-1))*MELD;
    for (int k=0;k<MELD;k+=4){
      float w0=W[(k+0)*256],w1=W[(k+1)*256],w2=W[(k+2)*256],w3=W[(k+3)*256];
      f4 v0=*(const f4*)(x0+k), v1=*(const f4*)(x1+k), v2=*(const f4*)(x2+k), v3=*(const f4*)(x3+k);
      a0 += w0*v0.x+w1*v0.y+w2*v0.z+w3*v0.w;
      a1 += w0*v1.x+w1*v1.y+w2*v1.z+w3*v1.w;
      a2 += w0*v2.x+w1*v2.y+w2*v2.z+w3*v2.w;
      a3 += w0*v3.x+w1*v3.y+w2*v3.z+w3*v3.w;
    }
  }
  f4 r; r.x=fmaxf(a0,0.f); r.y=fmaxf(a1,0.f); r.z=fmaxf(a2,0.f); r.w=fmaxf(a3,0.f);
  *(f4*)(ws + OFF_PN1 + (size_t)(t*HD + j)*NB + bq*4) = r;
}

// ---------- prenet layer2 ----------
__global__ void k_pre2(const float* __restrict__ pb2, float* __restrict__ ws){
  int t = BID >> 1;
  int j = ((BID & 1) * 64) + (TID & 63);
  int bq = TID >> 6;
  float b = pb2[j];
  f4 acc = {b,b,b,b};
  const float* W = ws + OFF_W2T + j;
  const float* A = ws + OFF_PN1 + (size_t)t*HD*NB + bq*4;
  #pragma unroll 4
  for (int k=0;k<HD;++k){
    float w = W[k*P2];
    f4 a = *(const f4*)(A + k*NB);
    acc.x += w*a.x; acc.y += w*a.y; acc.z += w*a.z; acc.w += w*a.w;
  }
  f4 r; r.x=fmaxf(acc.x,0.f); r.y=fmaxf(acc.y,0.f); r.z=fmaxf(acc.z,0.f); r.w=fmaxf(acc.w,0.f);
  *(f4*)(ws + OFF_PN2 + (size_t)(t*P2 + j)*NB + bq*4) = r;
}

// ---------- gipn = bih + pn2 @ wih[:, :128]^T  (all steps) ----------
__global__ void k_gipn(const float* __restrict__ gbih, float* __restrict__ ws){
  int t = BID / 12;
  int j = (BID % 12)*64 + (TID & 63);
  int bq = TID >> 6;
  float b = gbih[j];
  f4 acc = {b,b,b,b};
  const float* W = ws + OFF_WPNT + j;
  const float* A = ws + OFF_PN2 + (size_t)t*P2*NB + bq*4;
  #pragma unroll 4
  for (int k=0;k<P2;++k){
    float w = W[k*G3];
    f4 a = *(const f4*)(A + k*NB);
    acc.x += w*a.x; acc.y += w*a.y; acc.z += w*a.z; acc.w += w*a.w;
  }
  *(f4*)(ws + OFF_GIPN + (size_t)(t*G3 + j)*NB + bq*4) = acc;
}

// =========================================================================
// Persistent kernel (regular launch, manual grid barrier): 203 iters x 3 bars.
// Pipeline identical to round 3 (dependency table verified):
//   A(i): gi(i), gh(i), proj(i-1), d1-gates(i-2), d2-gates(i-3)
//   B(i): attn-gates+pq+energies(i), gi1(i-1), gh1(i-1)
//   C(i): softmax+ctx(i), gi2(i-2), gh2(i-2)
// =========================================================================
__global__ void __launch_bounds__(256, 1)
k_loop(float* __restrict__ ws, const float* __restrict__ enc,
       const float* __restrict__ av, const int* __restrict__ mlen,
       const float* __restrict__ gbhh, const float* __restrict__ pjb,
       const float* __restrict__ dbih, const float* __restrict__ dbhh,
       float* __restrict__ out){
  __shared__ float sh[4096];
  const int bid = BID;
  const int lane = TID & 63, bq = TID >> 6;
  unsigned nbar = 0;

  for (int i = 0; i <= TDEC + 2; ++i){
    // ================= PHASE A =================
    if (bid < 12){                       // gi(i) = gipn[i] + Watt^T . attention(i-1)
      const float* cp = ws + OFF_CTX;
      #pragma unroll
      for (int e=0;e<16;++e){ int id=TID+e*256; sh[id]=cp[id]+cp[id+4096]+cp[id+8192]; }
      __syncthreads();
      if (i < TDEC){
        int j = bid*64 + lane;
        f4 acc = *(const f4*)(ws + OFF_GIPN + ((size_t)i*G3 + j)*NB + bq*4);
        const float* W = ws + OFF_WATTT + j;
        #pragma unroll 4
        for (int k=0;k<HD;++k){
          float w = W[k*G3];
          f4 a = *(const f4*)&sh[k*NB + bq*4];
          acc.x += w*a.x; acc.y += w*a.y; acc.z += w*a.z; acc.w += w*a.w;
        }
        *(f4*)(ws + OFF_GI + j*NB + bq*4) = acc;
      }
    } else if (bid < 24){                // gh(i) = bhh + Whh^T . attn_h(i-1)
      if (i < TDEC){
        int j = (bid-12)*64 + lane;
        float bb = gbhh[j];
        f4 acc = {bb,bb,bb,bb};
        const float* W = ws + OFF_WHHT + j;
        const float* A = ws + OFF_ATTNH + ((i+1)&1)*4096 + bq*4;
        #pragma unroll 4
        for (int k=0;k<HD;++k){
          float w = W[k*G3];
          f4 a = *(const f4*)(A + k*NB);
          acc.x += w*a.x; acc.y += w*a.y; acc.z += w*a.z; acc.w += w*a.w;
        }
        *(f4*)(ws + OFF_GH + j*NB + bq*4) = acc;
      }
    } else if (bid < 28){                // proj(i-1) -> DECIN[(i-1)&1]
      const float* cp = ws + OFF_CTX;
      #pragma unroll
      for (int e=0;e<16;++e){ int id=TID+e*256; sh[id]=cp[id]+cp[id+4096]+cp[id+8192]; }
      __syncthreads();
      if (i >= 1 && i <= TDEC){
        int row = (bid-24)*64 + lane;
        float bb = pjb[row];
        f4 acc = {bb,bb,bb,bb};
        const float* W = ws + OFF_WPROJT + row;
        const float* Ah = ws + OFF_ATTNH + ((i+1)&1)*4096 + bq*4;
        #pragma unroll 4
        for (int k=0;k<HD;++k){
          float w = W[k*HD];
          f4 a = *(const f4*)(Ah + k*NB);
          acc.x += w*a.x; acc.y += w*a.y; acc.z += w*a.z; acc.w += w*a.w;
        }
        #pragma unroll 4
        for (int k=0;k<HD;++k){
          float w = W[(k+HD)*HD];
          f4 a = *(const f4*)&sh[k*NB + bq*4];
          acc.x += w*a.x; acc.y += w*a.y; acc.z += w*a.z; acc.w += w*a.w;
        }
        *(f4*)(ws + OFF_DECIN + ((i-1)&1)*4096 + row*NB + bq*4) = acc;
      }
    } else if (bid == 28){               // d1-gates(i-2): D1[i&1], DECIN1[i&1]
      if (i >= 2 && i <= TDEC+1){
        const float* gi1 = ws + OFF_GI1;
        const float* gh1 = ws + OFF_GH1;
        const float* hp  = ws + OFF_D1 + ((i+1)&1)*4096;
        float*       d1n = ws + OFF_D1 + (i&1)*4096;
        const float* din = ws + OFF_DECIN  + (i&1)*4096;
        float*       dn1 = ws + OFF_DECIN1 + (i&1)*4096;
        #pragma unroll
        for (int e=0;e<16;++e){
          int id = TID + e*256;
          float ir=gi1[id], iz=gi1[id+4096], in_=gi1[id+8192];
          float hr=gh1[id], hz=gh1[id+4096], hnn=gh1[id+8192];
          float h = hp[id];
          float rr=sigf(ir+hr), zz=sigf(iz+hz);
          float nn=tanhf_(in_+rr*hnn);
          float dn=(1.f-zz)*nn+zz*h;
          d1n[id]=dn;
          dn1[id]=dn+din[id];
        }
      }
    } else if (bid == 29){               // d2-gates(i-3): D2, D2O[i-3]
      if (i >= 3){
        const float* gi2 = ws + OFF_GI2;
        const float* gh2 = ws + OFF_GH2;
        float*       d2  = ws + OFF_D2;
        const float* dn1 = ws + OFF_DECIN1 + ((i+1)&1)*4096;
        float*       d2o = ws + OFF_D2O + (size_t)(i-3)*4096;
        #pragma unroll
        for (int e=0;e<16;++e){
          int id = TID + e*256;
          float ir=gi2[id], iz=gi2[id+4096], in_=gi2[id+8192];
          float hr=gh2[id], hz=gh2[id+4096], hnn=gh2[id+8192];
          float h = d2[id];
          float rr=sigf(ir+hr), zz=sigf(iz+hz);
          float nn=tanhf_(in_+rr*hnn);
          float dn=(1.f-zz)*nn+zz*h;
          d2[id]=dn;
          d2o[id]=dn+dn1[id];
        }
      }
    }
    gridbar(ws, ++nbar);

    // ================= PHASE B =================
    if (bid < 48){                       // attn gates + pq (LDS) + energies, per (b,ts)
      if (i < TDEC){
        int b = bid/3, ts = bid%3;
        {
          int d = TID, id = d*NB + b;
          const float* gi = ws + OFF_GI; const float* gh = ws + OFF_GH;
          float h = ws[OFF_ATTNH + ((i+1)&1)*4096 + id];
          float ir=gi[id], iz=gi[id+4096], in_=gi[id+8192];
          float hr=gh[id], hz=gh[id+4096], hnn=gh[id+8192];
          float rr=sigf(ir+hr), zz=sigf(iz+hz);
          float nn=tanhf_(in_+rr*hnn);
          float v=(1.f-zz)*nn+zz*h;
          sh[d]=v;
          if (ts==0) ws[OFF_ATTNH + (i&1)*4096 + id]=v;
        }
        __syncthreads();
        {
          int d = TID;
          const float* W = ws + OFF_WQT + d;
          float p = 0.f;
          #pragma unroll 4
          for (int k=0;k<HD;++k) p += W[k*HD]*sh[k];
          sh[256+d]=p;
        }
        __syncthreads();
        {
          int ks = TID>>7, tt = TID&127, t = ts*128+tt;
          const float* pmr = ws + OFF_PM + ((size_t)(b*TENC + t))*HD + ks*128;
          const float* q  = &sh[256 + ks*128];
          const float* vv = av + ks*128;
          float s = 0.f;
          #pragma unroll 4
          for (int d0=0; d0<128; d0+=4){
            f4 p = *(const f4*)(pmr+d0);
            f4 w = *(const f4*)(vv+d0);
            s += w.x*tanhf_(p.x+q[d0+0]) + w.y*tanhf_(p.y+q[d0+1])
               + w.z*tanhf_(p.z+q[d0+2]) + w.w*tanhf_(p.w+q[d0+3]);
          }
          sh[512+TID]=s;
        }
        __syncthreads();
        if (TID < 128){
          float e = sh[512+TID] + sh[512+TID+128];
          int len = mlen[bid/3];
          int tw = (bid%3)*128 + TID;
          ws[OFF_E + (bid/3)*TENC + tw] = (tw < len) ? e : -1e30f;
        }
      }
    } else if (bid < 60){                // gi1(i-1) from DECIN[(i-1)&1]
      if (i >= 1 && i <= TDEC){
        int j = (bid-48)*64 + lane;
        float bb = dbih[j];
        f4 acc = {bb,bb,bb,bb};
        const float* W = ws + OFF_WIH1T + j;
        const float* A = ws + OFF_DECIN + ((i-1)&1)*4096 + bq*4;
        #pragma unroll 4
        for (int k=0;k<HD;++k){
          float w = W[k*G3];
          f4 a = *(const f4*)(A + k*NB);
          acc.x += w*a.x; acc.y += w*a.y; acc.z += w*a.z; acc.w += w*a.w;
        }
        *(f4*)(ws + OFF_GI1 + j*NB + bq*4) = acc;
      }
    } else {                             // gh1(i-1) = bhh1 + Whh1^T . d1(i-2) [D1[i&1]]
      if (i >= 1 && i <= TDEC+1){
        int j = (bid-60)*64 + lane;
        float bb = dbhh[j];
        f4 acc = {bb,bb,bb,bb};
        const float* W = ws + OFF_WHH1T + j;
        const float* A = ws + OFF_D1 + (i&1)*4096 + bq*4;
        #pragma unroll 4
        for (int k=0;k<HD;++k){
          float w = W[k*G3];
          f4 a = *(const f4*)(A + k*NB);
          acc.x += w*a.x; acc.y += w*a.y; acc.z += w*a.z; acc.w += w*a.w;
        }
        *(f4*)(ws + OFF_GH1 + j*NB + bq*4) = acc;
      }
    }
    gridbar(ws, ++nbar);

    // ================= PHASE C =================
    if (bid < 48){                       // softmax (redundant x3) + context slice
      if (i < TDEC){
        int b = bid/3, ts = bid%3;
        const float* eb = ws + OFF_E + b*TENC;
        float m = -1e30f;
        for (int idx=TID; idx<TENC; idx+=256) m = fmaxf(m, eb[idx]);
        sh[TID]=m; __syncthreads();
        for (int s=128; s>0; s>>=1){ if (TID<s) sh[TID]=fmaxf(sh[TID],sh[TID+s]); __syncthreads(); }
        float M = sh[0]; __syncthreads();
        float sl = 0.f;
        for (int idx=TID; idx<TENC; idx+=256) sl += fexp2(1.44269504f*(eb[idx]-M));
        sh[TID]=sl; __syncthreads();
        for (int s=128; s>0; s>>=1){ if (TID<s) sh[TID]+=sh[TID+s]; __syncthreads(); }
        float inv = frcp(sh[0]); __syncthreads();
        if (TID < 128){
          int t = ts*128 + TID;
          float p = fexp2(1.44269504f*(eb[t]-M))*inv;
          sh[256+TID] = p;
          out[1280000 + (size_t)(b*TDEC + i)*TENC + t] = p;
        }
        __syncthreads();
        const float* encb = enc + ((size_t)(b*TENC + ts*128))*HD + TID;
        float ctx = 0.f;
        #pragma unroll 8
        for (int tt=0;tt<128;++tt) ctx += sh[256+tt]*encb[(size_t)tt*HD];
        ws[OFF_CTX + ts*4096 + TID*NB + b] = ctx;
      }
    } else if (bid < 60){                // gi2(i-2) from DECIN1[i&1]
      if (i >= 2 && i <= TDEC+1){
        int j = (bid-48)*64 + lane;
        float bb = dbih[G3 + j];
        f4 acc = {bb,bb,bb,bb};
        const float* W = ws + OFF_WIH2T + j;
        const float* A = ws + OFF_DECIN1 + (i&1)*4096 + bq*4;
        #pragma unroll 4
        for (int k=0;k<HD;++k){
          float w = W[k*G3];
          f4 a = *(const f4*)(A + k*NB);
          acc.x += w*a.x; acc.y += w*a.y; acc.z += w*a.z; acc.w += w*a.w;
        }
        *(f4*)(ws + OFF_GI2 + j*NB + bq*4) = acc;
      }
    } else {                             // gh2(i-2) = bhh2 + Whh2^T . d2(i-3) [D2]
      if (i >= 2 && i <= TDEC+1){
        int j = (bid-60)*64 + lane;
        float bb = dbhh[G3 + j];
        f4 acc = {bb,bb,bb,bb};
        const float* W = ws + OFF_WHH2T + j;
        const float* A = ws + OFF_D2 + bq*4;
        #pragma unroll 4
        for (int k=0;k<HD;++k){
          float w = W[k*G3];
          f4 a = *(const f4*)(A + k*NB);
          acc.x += w*a.x; acc.y += w*a.y; acc.z += w*a.z; acc.w += w*a.w;
        }
        *(f4*)(ws + OFF_GH2 + j*NB + bq*4) = acc;
      }
    }
    gridbar(ws, ++nbar);
  }
}

// ---------- mel projection (all steps) ----------
__global__ void k_mel(const float* __restrict__ ws, const float* __restrict__ mb, float* __restrict__ out){
  int t = BID/7, rb = (BID%7)*64;
  int j = rb + (TID&63), bq = TID>>6;
  if (j >= MELD) return;
  float bb = mb[j];
  f4 acc = {bb,bb,bb,bb};
  const float* W = ws + OFF_WMELT + j;
  const float* A = ws + OFF_D2O + (size_t)t*4096 + bq*4;
  #pragma unroll 4
  for (int k=0;k<HD;++k){
    float w = W[k*MELD];
    f4 a = *(const f4*)(A + k*NB);
    acc.x += w*a.x; acc.y += w*a.y; acc.z += w*a.z; acc.w += w*a.w;
  }
  out[(size_t)(bq*4+0)*80000 + t*MELD + j] = acc.x;
  out[(size_t)(bq*4+1)*80000 + t*MELD + j] = acc.y;
  out[(size_t)(bq*4+2)*80000 + t*MELD + j] = acc.z;
  out[(size_t)(bq*4+3)*80000 + t*MELD + j] = acc.w;
}

extern "C" void kernel_launch(void* const* d_in, const int* in_sizes, int n_in,
                              void* d_out, int out_size, void* d_ws, size_t ws_size,
                              hipStream_t stream) {
  const float* enc  = (const float*)d_in[0];
  const float* inp  = (const float*)d_in[1];
  const int*   mlen = (const int*)  d_in[2];
  const float* pw1  = (const float*)d_in[3];
  const float* pb1  = (const float*)d_in[4];
  const float* pw2  = (const float*)d_in[5];
  const float* pb2  = (const float*)d_in[6];
  const float* wmem = (const float*)d_in[7];
  const float* gwih = (const float*)d_in[8];
  const float* gwhh = (const float*)d_in[9];
  const float* gbih = (const float*)d_in[10];
  const float* gbhh = (const float*)d_in[11];
  const float* qw   = (const float*)d_in[12];
  const float* av   = (const float*)d_in[13];
  const float* pjw  = (const float*)d_in[14];
  const float* pjb  = (const float*)d_in[15];
  const float* dwih = (const float*)d_in[16];
  const float* dwhh = (const float*)d_in[17];
  const float* dbih = (const float*)d_in[18];
  const float* dbhh = (const float*)d_in[19];
  const float* mw   = (const float*)d_in[20];
  const float* mb   = (const float*)d_in[21];
  float* ws  = (float*)d_ws;
  float* out = (float*)d_out;

  k_init<<<32,256,0,stream>>>(ws);
  k_tr  <<<6944,256,0,stream>>>(pw1,pw2,wmem,gwih,gwhh,qw,pjw,dwih,dwhh,mw,ws);
  k_pm  <<<384,256,0,stream>>>(enc, ws);
  k_pre1<<<800,256,0,stream>>>(inp, pb1, ws);
  k_pre2<<<400,256,0,stream>>>(pb2, ws);
  k_gipn<<<2400,256,0,stream>>>(gbih, ws);

  k_loop<<<NBLK,256,0,stream>>>(ws, enc, av, mlen, gbhh, pjb, dbih, dbhh, out);

  k_mel<<<1400,256,0,stream>>>(ws, mb, out);
}

// Round 5
// 28354.651 us; speedup vs baseline: 2.5483x; 2.5483x over previous
//
#include <hip/hip_runtime.h>
#include <math.h>

#define TID ((int)threadIdx.x)
#define BID ((int)blockIdx.x)

typedef float4 f4;

// ---- dims ----
constexpr int NB   = 16;
constexpr int TENC = 384;
constexpr int TDEC = 200;
constexpr int HD   = 256;
constexpr int MELD = 400;
constexpr int P2   = 128;
constexpr int G3   = 768;
constexpr int NBLK = 64;    // persistent grid (all co-resident)

// ---- ws layout (float offsets) ----
constexpr int OFF_PM     = 0;                          // [16][384][256]
constexpr int OFF_GIPN   = OFF_PM     + NB*TENC*HD;    // [200][768][16]
constexpr int OFF_PN1    = OFF_GIPN   + TDEC*G3*NB;    // [200][256][16]
constexpr int OFF_PN2    = OFF_PN1    + TDEC*HD*NB;    // [200][128][16]
constexpr int OFF_D2O    = OFF_PN2    + TDEC*P2*NB;    // [200][256][16]
// zeroed region (33024 floats, contiguous):
constexpr int OFF_ATTNH  = OFF_D2O    + TDEC*HD*NB;    // [2][256][16]
constexpr int OFF_CTX    = OFF_ATTNH  + 2*4096;        // [256][16] (3 slots reserved)
constexpr int OFF_D1     = OFF_CTX    + 3*4096;        // [2][256][16]
constexpr int OFF_D2     = OFF_D1     + 2*4096;        // [256][16]
constexpr int OFF_BAR    = OFF_D2     + 4096;          // barrier counter (u32 at [0])
// unzeroed state:
constexpr int OFF_DECIN  = OFF_BAR    + 256;           // [2][256][16]
constexpr int OFF_DECIN1 = OFF_DECIN  + 2*4096;        // [2][256][16]
constexpr int OFF_GI     = OFF_DECIN1 + 2*4096;        // [768][16]
constexpr int OFF_GH     = OFF_GI     + 12288;
constexpr int OFF_GI1    = OFF_GH     + 12288;
constexpr int OFF_GH1    = OFF_GI1    + 12288;
constexpr int OFF_GI2    = OFF_GH1    + 12288;
constexpr int OFF_GH2    = OFF_GI2    + 12288;
constexpr int OFF_E      = OFF_GH2    + 12288;         // unused (kept for layout)
// transposed weights:
constexpr int OFF_W1T    = OFF_E      + NB*TENC;       // [400][256]
constexpr int OFF_W2T    = OFF_W1T    + 102400;        // [256][128]
constexpr int OFF_WMEMT  = OFF_W2T    + 32768;         // [256][256]
constexpr int OFF_WPNT   = OFF_WMEMT  + 65536;         // [128][768]
constexpr int OFF_WATTT  = OFF_WPNT   + 98304;         // [256][768]
constexpr int OFF_WHHT   = OFF_WATTT  + 196608;        // [256][768]
constexpr int OFF_WQT    = OFF_WHHT   + 196608;        // [256][256]
constexpr int OFF_WPROJT = OFF_WQT    + 65536;         // [512][256]
constexpr int OFF_WIH1T  = OFF_WPROJT + 131072;        // [256][768]
constexpr int OFF_WHH1T  = OFF_WIH1T  + 196608;
constexpr int OFF_WIH2T  = OFF_WHH1T  + 196608;
constexpr int OFF_WHH2T  = OFF_WIH2T  + 196608;
constexpr int OFF_WMELT  = OFF_WHH2T  + 196608;        // [256][400]

__device__ __forceinline__ float fexp2(float x){ return __builtin_amdgcn_exp2f(x); }
__device__ __forceinline__ float frcp(float x){ return __builtin_amdgcn_rcpf(x); }
__device__ __forceinline__ float sigf(float x){ return frcp(1.f + fexp2(-1.44269504f*x)); }
__device__ __forceinline__ float tanhf_(float x){ return 1.f - 2.f*frcp(1.f + fexp2(2.88539008f*x)); }

// ---- monotonic grid barrier.  Spin with RELAXED agent atomics (bypass L2 to
// coherence point, NO cache invalidate per poll — round-4's 165us/barrier was
// acquire-poll invalidating L2 every ~200cy).  One acquire load after exit
// (single L2 inv); release-add carries the L2 writeback. ----
__device__ __forceinline__ void gridbar(float* ws, unsigned target){
  unsigned* cnt = (unsigned*)(ws + OFF_BAR);
  __syncthreads();   // all block stores drained (vmcnt 0) before release
  if (TID == 0){
    __hip_atomic_fetch_add(cnt, 1u, __ATOMIC_RELEASE, __HIP_MEMORY_SCOPE_AGENT);
    while (__hip_atomic_load(cnt, __ATOMIC_RELAXED, __HIP_MEMORY_SCOPE_AGENT) < target)
      __builtin_amdgcn_s_sleep(2);
    (void)__hip_atomic_load(cnt, __ATOMIC_ACQUIRE, __HIP_MEMORY_SCOPE_AGENT);
  }
  __syncthreads();
}

// ---------- init: zero recurrent state + barrier (33024 floats) ----------
__global__ void k_init(float* ws){
  int g = BID*256 + TID;
  for (int idx = g; idx < 33024; idx += 32*256) ws[OFF_ATTNH + idx] = 0.f;
}

// ---------- transpose all weight matrices to k-major ----------
__global__ void k_tr(const float* pw1, const float* pw2, const float* wmem,
                     const float* gwih, const float* gwhh, const float* qw,
                     const float* pjw, const float* dwih, const float* dwhh,
                     const float* mw, float* ws){
  int g = BID*256 + TID;
  if (g < 102400){ int j=g%256,k=g/256; ws[OFF_W1T+g]=pw1[j*400+k]; return;} g-=102400;
  if (g < 32768){ int j=g%128,k=g/128; ws[OFF_W2T+g]=pw2[j*256+k]; return;} g-=32768;
  if (g < 65536){ int j=g%256,k=g/256; ws[OFF_WMEMT+g]=wmem[j*256+k]; return;} g-=65536;
  if (g < 98304){ int j=g%768,k=g/768; ws[OFF_WPNT+g]=gwih[j*384+k]; return;} g-=98304;
  if (g < 196608){ int j=g%768,k=g/768; ws[OFF_WATTT+g]=gwih[j*384+128+k]; return;} g-=196608;
  if (g < 196608){ int j=g%768,k=g/768; ws[OFF_WHHT+g]=gwhh[j*256+k]; return;} g-=196608;
  if (g < 65536){ int j=g%256,k=g/256; ws[OFF_WQT+g]=qw[j*256+k]; return;} g-=65536;
  if (g < 131072){ int j=g%256,k=g/256; ws[OFF_WPROJT+g]=pjw[j*512+k]; return;} g-=131072;
  if (g < 196608){ int j=g%768,k=g/768; ws[OFF_WIH1T+g]=dwih[j*256+k]; return;} g-=196608;
  if (g < 196608){ int j=g%768,k=g/768; ws[OFF_WHH1T+g]=dwhh[j*256+k]; return;} g-=196608;
  if (g < 196608){ int j=g%768,k=g/768; ws[OFF_WIH2T+g]=dwih[196608+j*256+k]; return;} g-=196608;
  if (g < 196608){ int j=g%768,k=g/768; ws[OFF_WHH2T+g]=dwhh[196608+j*256+k]; return;} g-=196608;
  if (g < 102400){ int j=g%400,k=g/400; ws[OFF_WMELT+g]=mw[j*256+k]; return;}
}

// ---------- processed_memory = enc @ mem_w^T ----------
__global__ void k_pm(const float* __restrict__ enc, float* __restrict__ ws){
  int b = BID / 24, t0 = (BID % 24) * 16;
  int d = TID;
  const float* W = ws + OFF_WMEMT + d;
  const float* A = enc + (size_t)(b*TENC + t0)*HD;
  float acc[16];
  #pragma unroll
  for (int tt=0; tt<16; ++tt) acc[tt]=0.f;
  for (int k=0; k<HD; k+=4){
    float w0=W[(k+0)*256], w1=W[(k+1)*256], w2=W[(k+2)*256], w3=W[(k+3)*256];
    #pragma unroll
    for (int tt=0; tt<16; ++tt){
      f4 a = *(const f4*)(A + tt*HD + k);
      acc[tt] += w0*a.x + w1*a.y + w2*a.z + w3*a.w;
    }
  }
  float* P = ws + OFF_PM + (size_t)(b*TENC + t0)*HD + d;
  #pragma unroll
  for (int tt=0; tt<16; ++tt) P[tt*HD] = acc[tt];
}

// ---------- prenet layer1 (all steps) ----------
__global__ void k_pre1(const float* __restrict__ inp, const float* __restrict__ pb1, float* __restrict__ ws){
  int t = BID >> 2;
  int j = ((BID & 3) * 64) + (TID & 63);
  int bq = TID >> 6;
  float b = pb1[j];
  float a0=b,a1=b,a2=b,a3=b;
  if (t > 0){
    const float* W = ws + OFF_W1T + j;
    const float* x0 = inp + (size_t)((bq*4+0)*TDEC + (t-1))*MELD;
    const float* x1 = inp + (size_t)((bq*4+1)*TDEC + (t-1))*MELD;
    const float* x2 = inp + (size_t)((bq*4+2)*TDEC + (t-1))*MELD;
    const float* x3 = inp + (size_t)((bq*4+3)*TDEC + (t-1))*MELD;
    for (int k=0;k<MELD;k+=4){
      float w0=W[(k+0)*256],w1=W[(k+1)*256],w2=W[(k+2)*256],w3=W[(k+3)*256];
      f4 v0=*(const f4*)(x0+k), v1=*(const f4*)(x1+k), v2=*(const f4*)(x2+k), v3=*(const f4*)(x3+k);
      a0 += w0*v0.x+w1*v0.y+w2*v0.z+w3*v0.w;
      a1 += w0*v1.x+w1*v1.y+w2*v1.z+w3*v1.w;
      a2 += w0*v2.x+w1*v2.y+w2*v2.z+w3*v2.w;
      a3 += w0*v3.x+w1*v3.y+w2*v3.z+w3*v3.w;
    }
  }
  f4 r; r.x=fmaxf(a0,0.f); r.y=fmaxf(a1,0.f); r.z=fmaxf(a2,0.f); r.w=fmaxf(a3,0.f);
  *(f4*)(ws + OFF_PN1 + (size_t)(t*HD + j)*NB + bq*4) = r;
}

// ---------- prenet layer2 ----------
__global__ void k_pre2(const float* __restrict__ pb2, float* __restrict__ ws){
  int t = BID >> 1;
  int j = ((BID & 1) * 64) + (TID & 63);
  int bq = TID >> 6;
  float b = pb2[j];
  f4 acc = {b,b,b,b};
  const float* W = ws + OFF_W2T + j;
  const float* A = ws + OFF_PN1 + (size_t)t*HD*NB + bq*4;
  #pragma unroll 4
  for (int k=0;k<HD;++k){
    float w = W[k*P2];
    f4 a = *(const f4*)(A + k*NB);
    acc.x += w*a.x; acc.y += w*a.y; acc.z += w*a.z; acc.w += w*a.w;
  }
  f4 r; r.x=fmaxf(acc.x,0.f); r.y=fmaxf(acc.y,0.f); r.z=fmaxf(acc.z,0.f); r.w=fmaxf(acc.w,0.f);
  *(f4*)(ws + OFF_PN2 + (size_t)(t*P2 + j)*NB + bq*4) = r;
}

// ---------- gipn = bih + pn2 @ wih[:, :128]^T  (all steps) ----------
__global__ void k_gipn(const float* __restrict__ gbih, float* __restrict__ ws){
  int t = BID / 12;
  int j = (BID % 12)*64 + (TID & 63);
  int bq = TID >> 6;
  float b = gbih[j];
  f4 acc = {b,b,b,b};
  const float* W = ws + OFF_WPNT + j;
  const float* A = ws + OFF_PN2 + (size_t)t*P2*NB + bq*4;
  #pragma unroll 4
  for (int k=0;k<P2;++k){
    float w = W[k*G3];
    f4 a = *(const f4*)(A + k*NB);
    acc.x += w*a.x; acc.y += w*a.y; acc.z += w*a.z; acc.w += w*a.w;
  }
  *(f4*)(ws + OFF_GIPN + (size_t)(t*G3 + j)*NB + bq*4) = acc;
}

// =========================================================================
// Persistent kernel: 203 iterations x 2 grid barriers.
// Phase A(i): gi(i) [0-11], gh(i) [12-23], proj(i-1) [24-27],
//             d1-gates(i-2) [28], d2-gates(i-3) [29]
// Phase B(i): attention full (gates+pq+energy+softmax+ctx) per b [0-15],
//             gi1(i-1) [16-27], gh1(i-1) [28-39],
//             gi2(i-2) [40-51], gh2(i-2) [52-63]
// Parity: x(t) stored at [t&1] for ATTNH/D1/DECIN/DECIN1.  First-use table:
//   gh(0)/gi(0) read zeroed ATTNH[1]/CTX @i=0.  gh1(0) reads zeroed D1[1] @i=1.
//   d1g(0) @i=2 reads zeroed D1[1]; gi2/gh2(0) @i=2 read DECIN1[0](A2)/zero D2.
//   d2g(0) @i=3 reads zeroed D2, DECIN1[0].
// =========================================================================
__global__ void __launch_bounds__(256, 1)
k_loop(float* __restrict__ ws, const float* __restrict__ enc,
       const float* __restrict__ av, const int* __restrict__ mlen,
       const float* __restrict__ gbhh, const float* __restrict__ pjb,
       const float* __restrict__ dbih, const float* __restrict__ dbhh,
       float* __restrict__ out){
  __shared__ float sh[1792];
  const int bid = BID;
  const int lane = TID & 63, bq = TID >> 6;
  unsigned nbar = 0;

  for (int i = 0; i <= TDEC + 2; ++i){
    // ================= PHASE A =================
    if (bid < 12){                       // gi(i) = gipn[i] + Watt^T . ctx(i-1)
      if (i < TDEC){
        int j = bid*64 + lane;
        f4 acc = *(const f4*)(ws + OFF_GIPN + ((size_t)i*G3 + j)*NB + bq*4);
        const float* W = ws + OFF_WATTT + j;
        const float* A = ws + OFF_CTX + bq*4;
        #pragma unroll 4
        for (int k=0;k<HD;++k){
          float w = W[k*G3];
          f4 a = *(const f4*)(A + k*NB);
          acc.x += w*a.x; acc.y += w*a.y; acc.z += w*a.z; acc.w += w*a.w;
        }
        *(f4*)(ws + OFF_GI + j*NB + bq*4) = acc;
      }
    } else if (bid < 24){                // gh(i) = bhh + Whh^T . attn_h(i-1)
      if (i < TDEC){
        int j = (bid-12)*64 + lane;
        float bb = gbhh[j];
        f4 acc = {bb,bb,bb,bb};
        const float* W = ws + OFF_WHHT + j;
        const float* A = ws + OFF_ATTNH + ((i+1)&1)*4096 + bq*4;
        #pragma unroll 4
        for (int k=0;k<HD;++k){
          float w = W[k*G3];
          f4 a = *(const f4*)(A + k*NB);
          acc.x += w*a.x; acc.y += w*a.y; acc.z += w*a.z; acc.w += w*a.w;
        }
        *(f4*)(ws + OFF_GH + j*NB + bq*4) = acc;
      }
    } else if (bid < 28){                // proj(i-1) -> DECIN[(i-1)&1]
      if (i >= 1 && i <= TDEC){
        int row = (bid-24)*64 + lane;
        float bb = pjb[row];
        f4 acc = {bb,bb,bb,bb};
        const float* W = ws + OFF_WPROJT + row;
        const float* Ah = ws + OFF_ATTNH + ((i+1)&1)*4096 + bq*4;
        const float* Ac = ws + OFF_CTX + bq*4;
        #pragma unroll 4
        for (int k=0;k<HD;++k){
          float w = W[k*HD];
          f4 a = *(const f4*)(Ah + k*NB);
          acc.x += w*a.x; acc.y += w*a.y; acc.z += w*a.z; acc.w += w*a.w;
        }
        #pragma unroll 4
        for (int k=0;k<HD;++k){
          float w = W[(k+HD)*HD];
          f4 a = *(const f4*)(Ac + k*NB);
          acc.x += w*a.x; acc.y += w*a.y; acc.z += w*a.z; acc.w += w*a.w;
        }
        *(f4*)(ws + OFF_DECIN + ((i-1)&1)*4096 + row*NB + bq*4) = acc;
      }
    } else if (bid == 28){               // d1-gates(i-2): D1[i&1], DECIN1[i&1]
      if (i >= 2 && i <= TDEC+1){
        const float* gi1 = ws + OFF_GI1;
        const float* gh1 = ws + OFF_GH1;
        const float* hp  = ws + OFF_D1 + ((i+1)&1)*4096;
        float*       d1n = ws + OFF_D1 + (i&1)*4096;
        const float* din = ws + OFF_DECIN  + (i&1)*4096;
        float*       dn1 = ws + OFF_DECIN1 + (i&1)*4096;
        #pragma unroll
        for (int e=0;e<16;++e){
          int id = TID + e*256;
          float ir=gi1[id], iz=gi1[id+4096], in_=gi1[id+8192];
          float hr=gh1[id], hz=gh1[id+4096], hnn=gh1[id+8192];
          float h = hp[id];
          float rr=sigf(ir+hr), zz=sigf(iz+hz);
          float nn=tanhf_(in_+rr*hnn);
          float dn=(1.f-zz)*nn+zz*h;
          d1n[id]=dn;
          dn1[id]=dn+din[id];
        }
      }
    } else if (bid == 29){               // d2-gates(i-3): D2, D2O[i-3]
      if (i >= 3){
        const float* gi2 = ws + OFF_GI2;
        const float* gh2 = ws + OFF_GH2;
        float*       d2  = ws + OFF_D2;
        const float* dn1 = ws + OFF_DECIN1 + ((i+1)&1)*4096;
        float*       d2o = ws + OFF_D2O + (size_t)(i-3)*4096;
        #pragma unroll
        for (int e=0;e<16;++e){
          int id = TID + e*256;
          float ir=gi2[id], iz=gi2[id+4096], in_=gi2[id+8192];
          float hr=gh2[id], hz=gh2[id+4096], hnn=gh2[id+8192];
          float h = d2[id];
          float rr=sigf(ir+hr), zz=sigf(iz+hz);
          float nn=tanhf_(in_+rr*hnn);
          float dn=(1.f-zz)*nn+zz*h;
          d2[id]=dn;
          d2o[id]=dn+dn1[id];
        }
      }
    }
    gridbar(ws, (++nbar)*NBLK);

    // ================= PHASE B =================
    if (bid < 16){                       // full attention for batch row b=bid
      if (i < TDEC){
        int b = bid;
        {  // attn-GRU gates -> attn_h(i)
          int id = TID*NB + b;
          const float* gi = ws + OFF_GI; const float* gh = ws + OFF_GH;
          float h = ws[OFF_ATTNH + ((i+1)&1)*4096 + id];
          float ir=gi[id], iz=gi[id+4096], in_=gi[id+8192];
          float hr=gh[id], hz=gh[id+4096], hnn=gh[id+8192];
          float rr=sigf(ir+hr), zz=sigf(iz+hz);
          float nn=tanhf_(in_+rr*hnn);
          float v=(1.f-zz)*nn+zz*h;
          sh[TID]=v;
          ws[OFF_ATTNH + (i&1)*4096 + id]=v;
        }
        __syncthreads();
        {  // pq = Wq^T . attn_h
          const float* W = ws + OFF_WQT + TID;
          float p = 0.f;
          #pragma unroll 4
          for (int k=0;k<HD;++k) p += W[k*HD]*sh[k];
          sh[256+TID]=p;
        }
        __syncthreads();
        int len = mlen[b];
        {  // energies: position TID, and 256+TID for TID<128
          const float* q = &sh[256];
          const float* pmr = ws + OFF_PM + ((size_t)(b*TENC + TID))*HD;
          float s = 0.f;
          #pragma unroll 4
          for (int d0=0; d0<HD; d0+=4){
            f4 p = *(const f4*)(pmr+d0);
            f4 w = *(const f4*)(av+d0);
            s += w.x*tanhf_(p.x+q[d0+0]) + w.y*tanhf_(p.y+q[d0+1])
               + w.z*tanhf_(p.z+q[d0+2]) + w.w*tanhf_(p.w+q[d0+3]);
          }
          sh[512+TID] = (TID < len) ? s : -1e30f;
          if (TID < 128){
            int t2 = 256 + TID;
            const float* pmr2 = ws + OFF_PM + ((size_t)(b*TENC + t2))*HD;
            float s2 = 0.f;
            #pragma unroll 4
            for (int d0=0; d0<HD; d0+=4){
              f4 p = *(const f4*)(pmr2+d0);
              f4 w = *(const f4*)(av+d0);
              s2 += w.x*tanhf_(p.x+q[d0+0]) + w.y*tanhf_(p.y+q[d0+1])
                  + w.z*tanhf_(p.z+q[d0+2]) + w.w*tanhf_(p.w+q[d0+3]);
            }
            sh[512+t2] = (t2 < len) ? s2 : -1e30f;
          }
        }
        __syncthreads();
        // softmax over sh[512..895] (384 energies)
        float e0 = sh[512+TID];
        float m = (TID < 128) ? fmaxf(e0, sh[768+TID]) : e0;
        sh[1536+TID]=m; __syncthreads();
        for (int s=128; s>0; s>>=1){ if (TID<s) sh[1536+TID]=fmaxf(sh[1536+TID],sh[1536+TID+s]); __syncthreads(); }
        float M = sh[1536]; __syncthreads();
        float p0 = fexp2(1.44269504f*(e0-M));
        float p1 = (TID < 128) ? fexp2(1.44269504f*(sh[768+TID]-M)) : 0.f;
        sh[1536+TID]=p0+p1; __syncthreads();
        for (int s=128; s>0; s>>=1){ if (TID<s) sh[1536+TID]+=sh[1536+TID+s]; __syncthreads(); }
        float inv = frcp(sh[1536]);
        float* alg = out + 1280000 + (size_t)(b*TDEC + i)*TENC;
        sh[896+TID] = p0*inv;
        alg[TID] = p0*inv;
        if (TID < 128){ sh[896+256+TID] = p1*inv; alg[256+TID] = p1*inv; }
        __syncthreads();
        {  // ctx[d] = sum_t p[t]*enc[b,t,d]
          const float* encb = enc + (size_t)b*TENC*HD + TID;
          float ctx = 0.f;
          #pragma unroll 8
          for (int tt=0;tt<TENC;++tt) ctx += sh[896+tt]*encb[(size_t)tt*HD];
          ws[OFF_CTX + TID*NB + b] = ctx;
        }
      }
    } else if (bid < 28){                // gi1(i-1) from DECIN[(i-1)&1]
      if (i >= 1 && i <= TDEC){
        int j = (bid-16)*64 + lane;
        float bb = dbih[j];
        f4 acc = {bb,bb,bb,bb};
        const float* W = ws + OFF_WIH1T + j;
        const float* A = ws + OFF_DECIN + ((i-1)&1)*4096 + bq*4;
        #pragma unroll 4
        for (int k=0;k<HD;++k){
          float w = W[k*G3];
          f4 a = *(const f4*)(A + k*NB);
          acc.x += w*a.x; acc.y += w*a.y; acc.z += w*a.z; acc.w += w*a.w;
        }
        *(f4*)(ws + OFF_GI1 + j*NB + bq*4) = acc;
      }
    } else if (bid < 40){                // gh1(i-1) = bhh1 + Whh1^T . d1(i-2) [D1[i&1]]
      if (i >= 1 && i <= TDEC){
        int j = (bid-28)*64 + lane;
        float bb = dbhh[j];
        f4 acc = {bb,bb,bb,bb};
        const float* W = ws + OFF_WHH1T + j;
        const float* A = ws + OFF_D1 + (i&1)*4096 + bq*4;
        #pragma unroll 4
        for (int k=0;k<HD;++k){
          float w = W[k*G3];
          f4 a = *(const f4*)(A + k*NB);
          acc.x += w*a.x; acc.y += w*a.y; acc.z += w*a.z; acc.w += w*a.w;
        }
        *(f4*)(ws + OFF_GH1 + j*NB + bq*4) = acc;
      }
    } else if (bid < 52){                // gi2(i-2) from DECIN1[i&1]
      if (i >= 2 && i <= TDEC+1){
        int j = (bid-40)*64 + lane;
        float bb = dbih[G3 + j];
        f4 acc = {bb,bb,bb,bb};
        const float* W = ws + OFF_WIH2T + j;
        const float* A = ws + OFF_DECIN1 + (i&1)*4096 + bq*4;
        #pragma unroll 4
        for (int k=0;k<HD;++k){
          float w = W[k*G3];
          f4 a = *(const f4*)(A + k*NB);
          acc.x += w*a.x; acc.y += w*a.y; acc.z += w*a.z; acc.w += w*a.w;
        }
        *(f4*)(ws + OFF_GI2 + j*NB + bq*4) = acc;
      }
    } else {                             // gh2(i-2) = bhh2 + Whh2^T . d2(i-3) [D2]
      if (i >= 2 && i <= TDEC+1){
        int j = (bid-52)*64 + lane;
        float bb = dbhh[G3 + j];
        f4 acc = {bb,bb,bb,bb};
        const float* W = ws + OFF_WHH2T + j;
        const float* A = ws + OFF_D2 + bq*4;
        #pragma unroll 4
        for (int k=0;k<HD;++k){
          float w = W[k*G3];
          f4 a = *(const f4*)(A + k*NB);
          acc.x += w*a.x; acc.y += w*a.y; acc.z += w*a.z; acc.w += w*a.w;
        }
        *(f4*)(ws + OFF_GH2 + j*NB + bq*4) = acc;
      }
    }
    gridbar(ws, (++nbar)*NBLK);
  }
}

// ---------- mel projection (all steps) ----------
__global__ void k_mel(const float* __restrict__ ws, const float* __restrict__ mb, float* __restrict__ out){
  int t = BID/7, rb = (BID%7)*64;
  int j = rb + (TID&63), bq = TID>>6;
  if (j >= MELD) return;
  float bb = mb[j];
  f4 acc = {bb,bb,bb,bb};
  const float* W = ws + OFF_WMELT + j;
  const float* A = ws + OFF_D2O + (size_t)t*4096 + bq*4;
  #pragma unroll 4
  for (int k=0;k<HD;++k){
    float w = W[k*MELD];
    f4 a = *(const f4*)(A + k*NB);
    acc.x += w*a.x; acc.y += w*a.y; acc.z += w*a.z; acc.w += w*a.w;
  }
  out[(size_t)(bq*4+0)*80000 + t*MELD + j] = acc.x;
  out[(size_t)(bq*4+1)*80000 + t*MELD + j] = acc.y;
  out[(size_t)(bq*4+2)*80000 + t*MELD + j] = acc.z;
  out[(size_t)(bq*4+3)*80000 + t*MELD + j] = acc.w;
}

extern "C" void kernel_launch(void* const* d_in, const int* in_sizes, int n_in,
                              void* d_out, int out_size, void* d_ws, size_t ws_size,
                              hipStream_t stream) {
  const float* enc  = (const float*)d_in[0];
  const float* inp  = (const float*)d_in[1];
  const int*   mlen = (const int*)  d_in[2];
  const float* pw1  = (const float*)d_in[3];
  const float* pb1  = (const float*)d_in[4];
  const float* pw2  = (const float*)d_in[5];
  const float* pb2  = (const float*)d_in[6];
  const float* wmem = (const float*)d_in[7];
  const float* gwih = (const float*)d_in[8];
  const float* gwhh = (const float*)d_in[9];
  const float* gbih = (const float*)d_in[10];
  const float* gbhh = (const float*)d_in[11];
  const float* qw   = (const float*)d_in[12];
  const float* av   = (const float*)d_in[13];
  const float* pjw  = (const float*)d_in[14];
  const float* pjb  = (const float*)d_in[15];
  const float* dwih = (const float*)d_in[16];
  const float* dwhh = (const float*)d_in[17];
  const float* dbih = (const float*)d_in[18];
  const float* dbhh = (const float*)d_in[19];
  const float* mw   = (const float*)d_in[20];
  const float* mb   = (const float*)d_in[21];
  float* ws  = (float*)d_ws;
  float* out = (float*)d_out;

  k_init<<<32,256,0,stream>>>(ws);
  k_tr  <<<6944,256,0,stream>>>(pw1,pw2,wmem,gwih,gwhh,qw,pjw,dwih,dwhh,mw,ws);
  k_pm  <<<384,256,0,stream>>>(enc, ws);
  k_pre1<<<800,256,0,stream>>>(inp, pb1, ws);
  k_pre2<<<400,256,0,stream>>>(pb2, ws);
  k_gipn<<<2400,256,0,stream>>>(gbih, ws);

  k_loop<<<NBLK,256,0,stream>>>(ws, enc, av, mlen, gbhh, pjb, dbih, dbhh, out);

  k_mel<<<1400,256,0,stream>>>(ws, mb, out);
}

// Round 6
// 23752.031 us; speedup vs baseline: 3.0421x; 1.1938x over previous
//
#include <hip/hip_runtime.h>
#include <math.h>

#define TID ((int)threadIdx.x)
#define BID ((int)blockIdx.x)

typedef float4 f4;

// ---- dims ----
constexpr int NB   = 16;
constexpr int TENC = 384;
constexpr int TDEC = 200;
constexpr int HD   = 256;
constexpr int MELD = 400;
constexpr int P2   = 128;
constexpr int G3   = 768;

// ---- ws layout (float offsets) ----
constexpr int OFF_PM     = 0;                          // [16][256][384]  (b, d, t) transposed!
constexpr int OFF_GIPN   = OFF_PM   + NB*HD*TENC;      // [16][200][768]  (b, t, j)
constexpr int OFF_PN1    = OFF_GIPN + NB*TDEC*G3;      // [200][256][16]
constexpr int OFF_PN2    = OFF_PN1  + TDEC*HD*NB;      // [200][128][16]
constexpr int OFF_D2O    = OFF_PN2  + TDEC*P2*NB;      // [16][200][256]  (b, t, d)
// transposed weights (k-major):
constexpr int OFF_W1T    = OFF_D2O  + NB*TDEC*HD;      // [400][256]
constexpr int OFF_W2T    = OFF_W1T    + 102400;        // [256][128]
constexpr int OFF_WMEMT  = OFF_W2T    + 32768;         // [256][256]
constexpr int OFF_WPNT   = OFF_WMEMT  + 65536;         // [128][768]
constexpr int OFF_WATTT  = OFF_WPNT   + 98304;         // [256][768]
constexpr int OFF_WHHT   = OFF_WATTT  + 196608;        // [256][768]
constexpr int OFF_WQT    = OFF_WHHT   + 196608;        // [256][256]
constexpr int OFF_WPROJT = OFF_WQT    + 65536;         // [512][256]
constexpr int OFF_WIH1T  = OFF_WPROJT + 131072;        // [256][768]
constexpr int OFF_WHH1T  = OFF_WIH1T  + 196608;
constexpr int OFF_WIH2T  = OFF_WHH1T  + 196608;
constexpr int OFF_WHH2T  = OFF_WIH2T  + 196608;
constexpr int OFF_WMELT  = OFF_WHH2T  + 196608;        // [256][400]

__device__ __forceinline__ float fexp2(float x){ return __builtin_amdgcn_exp2f(x); }
__device__ __forceinline__ float frcp(float x){ return __builtin_amdgcn_rcpf(x); }
__device__ __forceinline__ float sigf(float x){ return frcp(1.f + fexp2(-1.44269504f*x)); }
__device__ __forceinline__ float tanhf_(float x){ return 1.f - 2.f*frcp(1.f + fexp2(2.88539008f*x)); }

// ---------- transpose all weight matrices to k-major ----------
__global__ void k_tr(const float* pw1, const float* pw2, const float* wmem,
                     const float* gwih, const float* gwhh, const float* qw,
                     const float* pjw, const float* dwih, const float* dwhh,
                     const float* mw, float* ws){
  int g = BID*256 + TID;
  if (g < 102400){ int j=g%256,k=g/256; ws[OFF_W1T+g]=pw1[j*400+k]; return;} g-=102400;
  if (g < 32768){ int j=g%128,k=g/128; ws[OFF_W2T+g]=pw2[j*256+k]; return;} g-=32768;
  if (g < 65536){ int j=g%256,k=g/256; ws[OFF_WMEMT+g]=wmem[j*256+k]; return;} g-=65536;
  if (g < 98304){ int j=g%768,k=g/768; ws[OFF_WPNT+g]=gwih[j*384+k]; return;} g-=98304;
  if (g < 196608){ int j=g%768,k=g/768; ws[OFF_WATTT+g]=gwih[j*384+128+k]; return;} g-=196608;
  if (g < 196608){ int j=g%768,k=g/768; ws[OFF_WHHT+g]=gwhh[j*256+k]; return;} g-=196608;
  if (g < 65536){ int j=g%256,k=g/256; ws[OFF_WQT+g]=qw[j*256+k]; return;} g-=65536;
  if (g < 131072){ int j=g%256,k=g/256; ws[OFF_WPROJT+g]=pjw[j*512+k]; return;} g-=131072;
  if (g < 196608){ int j=g%768,k=g/768; ws[OFF_WIH1T+g]=dwih[j*256+k]; return;} g-=196608;
  if (g < 196608){ int j=g%768,k=g/768; ws[OFF_WHH1T+g]=dwhh[j*256+k]; return;} g-=196608;
  if (g < 196608){ int j=g%768,k=g/768; ws[OFF_WIH2T+g]=dwih[196608+j*256+k]; return;} g-=196608;
  if (g < 196608){ int j=g%768,k=g/768; ws[OFF_WHH2T+g]=dwhh[196608+j*256+k]; return;} g-=196608;
  if (g < 102400){ int j=g%400,k=g/400; ws[OFF_WMELT+g]=mw[j*256+k]; return;}
}

// ---------- processed_memory (stored TRANSPOSED: [b][d][t]) ----------
__global__ void k_pm(const float* __restrict__ enc, float* __restrict__ ws){
  int b = BID / 24, t0 = (BID % 24) * 16;
  int d = TID;
  const float* W = ws + OFF_WMEMT + d;
  const float* A = enc + (size_t)(b*TENC + t0)*HD;
  float acc[16];
  #pragma unroll
  for (int tt=0; tt<16; ++tt) acc[tt]=0.f;
  for (int k=0; k<HD; k+=4){
    float w0=W[(k+0)*256], w1=W[(k+1)*256], w2=W[(k+2)*256], w3=W[(k+3)*256];
    #pragma unroll
    for (int tt=0; tt<16; ++tt){
      f4 a = *(const f4*)(A + tt*HD + k);
      acc[tt] += w0*a.x + w1*a.y + w2*a.z + w3*a.w;
    }
  }
  float* P = ws + OFF_PM + ((size_t)(b*HD + d))*TENC + t0;
  #pragma unroll
  for (int tt=0; tt<16; ++tt) P[tt] = acc[tt];
}

// ---------- prenet layer1 (all steps) ----------
__global__ void k_pre1(const float* __restrict__ inp, const float* __restrict__ pb1, float* __restrict__ ws){
  int t = BID >> 2;
  int j = ((BID & 3) * 64) + (TID & 63);
  int bq = TID >> 6;
  float b = pb1[j];
  float a0=b,a1=b,a2=b,a3=b;
  if (t > 0){
    const float* W = ws + OFF_W1T + j;
    const float* x0 = inp + (size_t)((bq*4+0)*TDEC + (t-1))*MELD;
    const float* x1 = inp + (size_t)((bq*4+1)*TDEC + (t-1))*MELD;
    const float* x2 = inp + (size_t)((bq*4+2)*TDEC + (t-1))*MELD;
    const float* x3 = inp + (size_t)((bq*4+3)*TDEC + (t-1))*MELD;
    for (int k=0;k<MELD;k+=4){
      float w0=W[(k+0)*256],w1=W[(k+1)*256],w2=W[(k+2)*256],w3=W[(k+3)*256];
      f4 v0=*(const f4*)(x0+k), v1=*(const f4*)(x1+k), v2=*(const f4*)(x2+k), v3=*(const f4*)(x3+k);
      a0 += w0*v0.x+w1*v0.y+w2*v0.z+w3*v0.w;
      a1 += w0*v1.x+w1*v1.y+w2*v1.z+w3*v1.w;
      a2 += w0*v2.x+w1*v2.y+w2*v2.z+w3*v2.w;
      a3 += w0*v3.x+w1*v3.y+w2*v3.z+w3*v3.w;
    }
  }
  f4 r; r.x=fmaxf(a0,0.f); r.y=fmaxf(a1,0.f); r.z=fmaxf(a2,0.f); r.w=fmaxf(a3,0.f);
  *(f4*)(ws + OFF_PN1 + (size_t)(t*HD + j)*NB + bq*4) = r;
}

// ---------- prenet layer2 ----------
__global__ void k_pre2(const float* __restrict__ pb2, float* __restrict__ ws){
  int t = BID >> 1;
  int j = ((BID & 1) * 64) + (TID & 63);
  int bq = TID >> 6;
  float b = pb2[j];
  f4 acc = {b,b,b,b};
  const float* W = ws + OFF_W2T + j;
  const float* A = ws + OFF_PN1 + (size_t)t*HD*NB + bq*4;
  #pragma unroll 4
  for (int k=0;k<HD;++k){
    float w = W[k*P2];
    f4 a = *(const f4*)(A + k*NB);
    acc.x += w*a.x; acc.y += w*a.y; acc.z += w*a.z; acc.w += w*a.w;
  }
  f4 r; r.x=fmaxf(acc.x,0.f); r.y=fmaxf(acc.y,0.f); r.z=fmaxf(acc.z,0.f); r.w=fmaxf(acc.w,0.f);
  *(f4*)(ws + OFF_PN2 + (size_t)(t*P2 + j)*NB + bq*4) = r;
}

// ---------- gipn = bih + pn2 @ wih[:, :128]^T  (stored [b][t][768]) ----------
__global__ void k_gipn(const float* __restrict__ gbih, float* __restrict__ ws){
  int t = BID / 12;
  int j = (BID % 12)*64 + (TID & 63);
  int bq = TID >> 6;
  float b = gbih[j];
  f4 acc = {b,b,b,b};
  const float* W = ws + OFF_WPNT + j;
  const float* A = ws + OFF_PN2 + (size_t)t*P2*NB + bq*4;
  #pragma unroll 4
  for (int k=0;k<P2;++k){
    float w = W[k*G3];
    f4 a = *(const f4*)(A + k*NB);
    acc.x += w*a.x; acc.y += w*a.y; acc.z += w*a.z; acc.w += w*a.w;
  }
  ws[OFF_GIPN + ((size_t)((bq*4+0)*TDEC + t))*G3 + j] = acc.x;
  ws[OFF_GIPN + ((size_t)((bq*4+1)*TDEC + t))*G3 + j] = acc.y;
  ws[OFF_GIPN + ((size_t)((bq*4+2)*TDEC + t))*G3 + j] = acc.z;
  ws[OFF_GIPN + ((size_t)((bq*4+3)*TDEC + t))*G3 + j] = acc.w;
}

// =========================================================================
// Fully block-local recurrence: 1 block per batch row, 1024 threads,
// ZERO grid barriers.  All recurrent state in LDS; weights stream from
// L2/L3 (never invalidated).  Per step, sequential stages with cheap
// __syncthreads between them.
// =========================================================================
__global__ void __launch_bounds__(1024, 1)
k_loop(float* __restrict__ ws, const float* __restrict__ enc,
       const float* __restrict__ av, const int* __restrict__ mlen,
       const float* __restrict__ gbhh, const float* __restrict__ pjb,
       const float* __restrict__ dbih, const float* __restrict__ dbhh,
       float* __restrict__ out){
  const int b = BID;
  const int tid = TID;
  __shared__ __align__(16) float sCtx[256], sAhp[256], sAhn[256];
  __shared__ __align__(16) float sD1p[256], sD1n[256], sD2[256];
  __shared__ __align__(16) float sDin[256], sDin1[256];
  __shared__ __align__(16) float sGi[768], sGh[768];
  __shared__ __align__(16) float sPq[256], sAv[256], sEn[384], sPr[384], sRed[256];

  if (tid < 256){
    sCtx[tid]=0.f; sAhp[tid]=0.f; sD1p[tid]=0.f; sD2[tid]=0.f;
    sAv[tid]=av[tid];
  }
  const int len = mlen[b];
  const float* pmt  = ws + OFF_PM   + (size_t)b*HD*TENC;
  const float* encb = enc + (size_t)b*TENC*HD;
  __syncthreads();

  for (int t = 0; t < TDEC; ++t){
    // S1: gi = gipn + Watt^T.ctx ; gh = bhh + Whh^T.ahp
    const float* gipn_bt = ws + OFF_GIPN + ((size_t)(b*TDEC + t))*G3;
    for (int task = tid; task < 1536; task += 1024){
      if (task < 768){
        int j = task;
        const float* W = ws + OFF_WATTT + j;
        float acc = gipn_bt[j];
        #pragma unroll 4
        for (int k=0;k<HD;k+=4){
          f4 x = *(const f4*)&sCtx[k];
          acc += W[(k+0)*G3]*x.x + W[(k+1)*G3]*x.y + W[(k+2)*G3]*x.z + W[(k+3)*G3]*x.w;
        }
        sGi[j] = acc;
      } else {
        int j = task - 768;
        const float* W = ws + OFF_WHHT + j;
        float acc = gbhh[j];
        #pragma unroll 4
        for (int k=0;k<HD;k+=4){
          f4 x = *(const f4*)&sAhp[k];
          acc += W[(k+0)*G3]*x.x + W[(k+1)*G3]*x.y + W[(k+2)*G3]*x.z + W[(k+3)*G3]*x.w;
        }
        sGh[j] = acc;
      }
    }
    __syncthreads();
    // S2: attention-GRU gates
    if (tid < 256){
      float ir=sGi[tid], iz=sGi[tid+256], in_=sGi[tid+512];
      float hr=sGh[tid], hz=sGh[tid+256], hnn=sGh[tid+512];
      float h = sAhp[tid];
      float rr=sigf(ir+hr), zz=sigf(iz+hz);
      float nn=tanhf_(in_+rr*hnn);
      sAhn[tid] = (1.f-zz)*nn + zz*h;
    }
    __syncthreads();
    // S3: pq = Wq^T . ahn
    if (tid < 256){
      const float* W = ws + OFF_WQT + tid;
      float p = 0.f;
      #pragma unroll 4
      for (int k=0;k<HD;k+=4){
        f4 x = *(const f4*)&sAhn[k];
        p += W[(k+0)*HD]*x.x + W[(k+1)*HD]*x.y + W[(k+2)*HD]*x.z + W[(k+3)*HD]*x.w;
      }
      sPq[tid]=p;
    }
    __syncthreads();
    // S4: energies (PM transposed -> coalesced over positions)
    if (tid < TENC){
      const float* pmc = pmt + tid;
      float s = 0.f;
      #pragma unroll 4
      for (int d=0; d<HD; ++d)
        s += sAv[d]*tanhf_(pmc[(size_t)d*TENC] + sPq[d]);
      sEn[tid] = (tid < len) ? s : -1e30f;
    }
    __syncthreads();
    // S5: softmax over 384
    if (tid < 256){
      float m = sEn[tid];
      if (tid < 128) m = fmaxf(m, sEn[256+tid]);
      sRed[tid]=m;
    }
    __syncthreads();
    for (int s=128; s>0; s>>=1){ if (tid<s) sRed[tid]=fmaxf(sRed[tid],sRed[tid+s]); __syncthreads(); }
    float M = sRed[0];
    __syncthreads();
    if (tid < 256){
      float p0 = fexp2(1.44269504f*(sEn[tid]-M));
      sPr[tid]=p0;
      float p1 = 0.f;
      if (tid < 128){ p1 = fexp2(1.44269504f*(sEn[256+tid]-M)); sPr[256+tid]=p1; }
      sRed[tid]=p0+p1;
    }
    __syncthreads();
    for (int s=128; s>0; s>>=1){ if (tid<s) sRed[tid]+=sRed[tid+s]; __syncthreads(); }
    float inv = frcp(sRed[0]);
    __syncthreads();
    if (tid < TENC){
      float p = sPr[tid]*inv;
      sPr[tid]=p;
      out[1280000 + (size_t)(b*TDEC + t)*TENC + tid] = p;
    }
    __syncthreads();
    // S6: ctx = sum_t p[t] * enc[b,t,:]
    if (tid < 256){
      const float* e = encb + tid;
      float c = 0.f;
      #pragma unroll 4
      for (int tt=0; tt<TENC; ++tt) c += sPr[tt]*e[(size_t)tt*HD];
      sCtx[tid]=c;
    }
    __syncthreads();
    // S7: dec_in = proj([ahn, ctx])
    if (tid < 256){
      const float* W = ws + OFF_WPROJT + tid;
      float acc = pjb[tid];
      #pragma unroll 4
      for (int k=0;k<HD;k+=4){
        f4 x = *(const f4*)&sAhn[k];
        acc += W[(k+0)*HD]*x.x + W[(k+1)*HD]*x.y + W[(k+2)*HD]*x.z + W[(k+3)*HD]*x.w;
      }
      #pragma unroll 4
      for (int k=0;k<HD;k+=4){
        f4 x = *(const f4*)&sCtx[k];
        acc += W[(HD+k+0)*HD]*x.x + W[(HD+k+1)*HD]*x.y + W[(HD+k+2)*HD]*x.z + W[(HD+k+3)*HD]*x.w;
      }
      sDin[tid]=acc;
    }
    __syncthreads();
    // S8: gi1 = bih1 + Wih1^T.din ; gh1 = bhh1 + Whh1^T.d1p
    for (int task = tid; task < 1536; task += 1024){
      if (task < 768){
        int j = task;
        const float* W = ws + OFF_WIH1T + j;
        float acc = dbih[j];
        #pragma unroll 4
        for (int k=0;k<HD;k+=4){
          f4 x = *(const f4*)&sDin[k];
          acc += W[(k+0)*G3]*x.x + W[(k+1)*G3]*x.y + W[(k+2)*G3]*x.z + W[(k+3)*G3]*x.w;
        }
        sGi[j] = acc;
      } else {
        int j = task - 768;
        const float* W = ws + OFF_WHH1T + j;
        float acc = dbhh[j];
        #pragma unroll 4
        for (int k=0;k<HD;k+=4){
          f4 x = *(const f4*)&sD1p[k];
          acc += W[(k+0)*G3]*x.x + W[(k+1)*G3]*x.y + W[(k+2)*G3]*x.z + W[(k+3)*G3]*x.w;
        }
        sGh[j] = acc;
      }
    }
    __syncthreads();
    // S9: d1 gates
    if (tid < 256){
      float ir=sGi[tid], iz=sGi[tid+256], in_=sGi[tid+512];
      float hr=sGh[tid], hz=sGh[tid+256], hnn=sGh[tid+512];
      float h = sD1p[tid];
      float rr=sigf(ir+hr), zz=sigf(iz+hz);
      float nn=tanhf_(in_+rr*hnn);
      float dn=(1.f-zz)*nn+zz*h;
      sD1n[tid]=dn;
      sDin1[tid]=dn+sDin[tid];
    }
    __syncthreads();
    // S10: gi2 = bih2 + Wih2^T.din1 ; gh2 = bhh2 + Whh2^T.d2
    for (int task = tid; task < 1536; task += 1024){
      if (task < 768){
        int j = task;
        const float* W = ws + OFF_WIH2T + j;
        float acc = dbih[G3 + j];
        #pragma unroll 4
        for (int k=0;k<HD;k+=4){
          f4 x = *(const f4*)&sDin1[k];
          acc += W[(k+0)*G3]*x.x + W[(k+1)*G3]*x.y + W[(k+2)*G3]*x.z + W[(k+3)*G3]*x.w;
        }
        sGi[j] = acc;
      } else {
        int j = task - 768;
        const float* W = ws + OFF_WHH2T + j;
        float acc = dbhh[G3 + j];
        #pragma unroll 4
        for (int k=0;k<HD;k+=4){
          f4 x = *(const f4*)&sD2[k];
          acc += W[(k+0)*G3]*x.x + W[(k+1)*G3]*x.y + W[(k+2)*G3]*x.z + W[(k+3)*G3]*x.w;
        }
        sGh[j] = acc;
      }
    }
    __syncthreads();
    // S11: d2 gates + d2o store + state rotate
    if (tid < 256){
      float ir=sGi[tid], iz=sGi[tid+256], in_=sGi[tid+512];
      float hr=sGh[tid], hz=sGh[tid+256], hnn=sGh[tid+512];
      float h = sD2[tid];
      float rr=sigf(ir+hr), zz=sigf(iz+hz);
      float nn=tanhf_(in_+rr*hnn);
      float dn=(1.f-zz)*nn+zz*h;
      sD2[tid]=dn;
      ws[OFF_D2O + (size_t)(b*TDEC + t)*HD + tid] = dn + sDin1[tid];
      sAhp[tid]=sAhn[tid];
      sD1p[tid]=sD1n[tid];
    }
    __syncthreads();
  }
}

// ---------- mel projection: block = (b, 8-step chunk), weights amortized ----------
__global__ void k_mel(const float* __restrict__ ws, const float* __restrict__ mb, float* __restrict__ out){
  __shared__ __align__(16) float s[8][256];
  int b = BID / 25, t0 = (BID % 25) * 8;
  const float* src = ws + OFF_D2O + (size_t)(b*TDEC + t0)*HD;
  for (int idx = TID; idx < 8*256; idx += 512){
    s[idx>>8][idx&255] = src[idx];
  }
  __syncthreads();
  int j = TID;
  if (j < MELD){
    float bb = mb[j];
    float acc[8];
    #pragma unroll
    for (int c=0;c<8;++c) acc[c]=bb;
    const float* W = ws + OFF_WMELT + j;
    #pragma unroll 2
    for (int k=0;k<HD;++k){
      float w = W[k*MELD];
      #pragma unroll
      for (int c=0;c<8;++c) acc[c] += w*s[c][k];
    }
    #pragma unroll
    for (int c=0;c<8;++c)
      out[(size_t)b*80000 + (size_t)(t0+c)*MELD + j] = acc[c];
  }
}

extern "C" void kernel_launch(void* const* d_in, const int* in_sizes, int n_in,
                              void* d_out, int out_size, void* d_ws, size_t ws_size,
                              hipStream_t stream) {
  const float* enc  = (const float*)d_in[0];
  const float* inp  = (const float*)d_in[1];
  const int*   mlen = (const int*)  d_in[2];
  const float* pw1  = (const float*)d_in[3];
  const float* pb1  = (const float*)d_in[4];
  const float* pw2  = (const float*)d_in[5];
  const float* pb2  = (const float*)d_in[6];
  const float* wmem = (const float*)d_in[7];
  const float* gwih = (const float*)d_in[8];
  const float* gwhh = (const float*)d_in[9];
  const float* gbih = (const float*)d_in[10];
  const float* gbhh = (const float*)d_in[11];
  const float* qw   = (const float*)d_in[12];
  const float* av   = (const float*)d_in[13];
  const float* pjw  = (const float*)d_in[14];
  const float* pjb  = (const float*)d_in[15];
  const float* dwih = (const float*)d_in[16];
  const float* dwhh = (const float*)d_in[17];
  const float* dbih = (const float*)d_in[18];
  const float* dbhh = (const float*)d_in[19];
  const float* mw   = (const float*)d_in[20];
  const float* mb   = (const float*)d_in[21];
  float* ws  = (float*)d_ws;
  float* out = (float*)d_out;

  k_tr  <<<6944,256,0,stream>>>(pw1,pw2,wmem,gwih,gwhh,qw,pjw,dwih,dwhh,mw,ws);
  k_pm  <<<384,256,0,stream>>>(enc, ws);
  k_pre1<<<800,256,0,stream>>>(inp, pb1, ws);
  k_pre2<<<400,256,0,stream>>>(pb2, ws);
  k_gipn<<<2400,256,0,stream>>>(gbih, ws);

  k_loop<<<NB,1024,0,stream>>>(ws, enc, av, mlen, gbhh, pjb, dbih, dbhh, out);

  k_mel<<<400,512,0,stream>>>(ws, mb, out);
}